// Round 15
// baseline (991.574 us; speedup 1.0000x reference)
//
#include <hip/hip_runtime.h>
#include <hip/hip_bf16.h>
#include <math.h>

#define N_NODES 5000
#define N_STRUCT 50
#define PER 100
#define K_NB 24
#define N_EDGES (N_NODES*K_NB)
#define TMAX 32
#define D 128
#define FF 512
#define NTOK (N_NODES*TMAX)

typedef short bf16x8 __attribute__((ext_vector_type(8)));
typedef float f32x4  __attribute__((ext_vector_type(4)));
#define MFMA_B16(a,b,c) __builtin_amdgcn_mfma_f32_16x16x32_bf16(a,b,c,0,0,0)

__device__ __forceinline__ short f2bf(float x){           // round-half-up float->bf16 (2 ops)
    return (short)((__float_as_uint(x) + 0x8000u) >> 16);
}
__device__ __forceinline__ short f2bf_rn(float x){        // RTNE (weights only)
    unsigned u = __float_as_uint(x);
    return (short)((u + 0x7FFFu + ((u>>16)&1u)) >> 16);
}

__device__ __forceinline__ float gelu_f(float x){
    // x*sigmoid(2u) == 0.5x(1+tanh(u)); 1 exp + 1 rcp
    float arg = x * fmaf(x*x, -0.07135481627f, -1.5957691216057308f);  // -2u
    return x * __builtin_amdgcn_rcpf(1.f + __expf(arg));
}

__device__ __forceinline__ float cutoff_f(float r){
    if (r < 3.f) return 1.f;
    if (r >= 5.f) return 0.f;
    float x = (r-3.f)*0.5f;
    return 0.5f*(1.f + cosf(3.14159265358979323846f * x));
}

// === Merged setup: [0,3200) wt | [3200,3669) edge | [3669,3689) elem | 3689 prep | 3690 comp-init
__global__ void k_setup(const float* tWq, const float* tWk, const float* tWv, const float* tWo,
                        const float* tW1, const float* tW2, const float* gWq, const float* gWk,
                        const float* gWv, const float* gWo, const float* gW1, const float* gW2,
                        const float* gct, short* __restrict__ WT,
                        const float* __restrict__ pos, const float* __restrict__ cells,
                        const float* __restrict__ shifts, const int* __restrict__ centers,
                        const int* __restrict__ neighbors, float* __restrict__ EV,
                        float* __restrict__ RAD, int* __restrict__ CORR,
                        const int* __restrict__ numbers, int* __restrict__ ELEM,
                        const float* __restrict__ Wcart, const float* __restrict__ embc,
                        const float* __restrict__ embn, const float* __restrict__ Wcomp,
                        float* __restrict__ W3, float* __restrict__ ECn, float* __restrict__ ENn,
                        const float* __restrict__ cw, float* __restrict__ out){
    int b = blockIdx.x, tid = threadIdx.x;
    if (b < 3200){   // weight transpose+bf16; Wq gets 1/sqrt(32) folded
        const int  sel[25]  = {0,0,1,1,2,2,3,3,4,4,5,5,6,6,7,7,8,8,9,9,10,10,11,11,12};
        const int  lin[25]  = {7,7,7,7,7,7,7,7,7,7,9,9,7,7,7,7,7,7,7,7,7,7,9,9,8};
        const int  lout[25] = {7,7,7,7,7,7,7,7,9,9,7,7,7,7,7,7,7,7,7,7,9,9,7,7,7};
        const int  soff[25] = {0,16384,0,16384,0,16384,0,16384,0,65536,0,65536,
                               0,16384,0,16384,0,16384,0,16384,0,65536,0,65536,0};
        const int  doff[25] = {0,16384,32768,49152,65536,81920,98304,114688,
                               131072,196608,262144,327680,
                               393216,409600,425984,442368,458752,475136,491520,507904,
                               524288,589824,655360,720896,786432};
        int gid = b*256 + tid;
        int r = 0, base = 0;
        while (true){
            int sz = 1 << (lin[r]+lout[r]);
            if (gid < base + sz) break;
            base += sz; r++;
        }
        int d = gid - base;
        int j = d >> lin[r], i = d & ((1<<lin[r])-1);
        const float* src;
        switch (sel[r]){
            case 0: src=tWq; break; case 1: src=tWk; break; case 2: src=tWv; break; case 3: src=tWo; break;
            case 4: src=tW1; break; case 5: src=tW2; break;
            case 6: src=gWq; break; case 7: src=gWk; break; case 8: src=gWv; break; case 9: src=gWo; break;
            case 10: src=gW1; break; case 11: src=gW2; break; default: src=gct; break;
        }
        float v = src[soff[r] + (i<<lout[r]) + j];
        if (sel[r] == 0 || sel[r] == 6) v *= 0.17677669529663689f;
        WT[doff[r] + d] = f2bf_rn(v);
    } else if (b < 3669){   // edge vectors + cutoff + reverse-edge
        int e = (b-3200)*256 + tid;
        if (e >= N_EDGES) return;
        int c = centers[e], nb = neighbors[e];
        int st = c / PER;
        const float* cell = cells + st*9;
        float s0 = shifts[e*3+0], s1 = shifts[e*3+1], s2 = shifts[e*3+2];
        float ex = pos[nb*3+0]-pos[c*3+0] + s0*cell[0]+s1*cell[3]+s2*cell[6];
        float ey = pos[nb*3+1]-pos[c*3+1] + s0*cell[1]+s1*cell[4]+s2*cell[7];
        float ez = pos[nb*3+2]-pos[c*3+2] + s0*cell[2]+s1*cell[5]+s2*cell[8];
        EV[e*3+0] = ex; EV[e*3+1] = ey; EV[e*3+2] = ez;
        RAD[e] = cutoff_f(sqrtf(ex*ex+ey*ey+ez*ez));
        int base2 = nb*K_NB, corr = base2;
        for (int k2 = 0; k2 < K_NB; k2++){
            if (neighbors[base2+k2] == c){ corr = base2+k2; break; }
        }
        CORR[e] = corr;
    } else if (b < 3689){   // element map
        int i = (b-3669)*256 + tid;
        if (i < N_NODES){
            int z = numbers[i];
            ELEM[i] = (z==1)?0:(z==6)?1:(z==7)?2:(z==8)?3:-1;
        }
    } else if (b == 3689){  // encoder weight precontract
        if (tid >= 128) return;
        int j = tid;
        for (int a = 0; a < 3; a++){
            float s = 0;
            for (int i = 0; i < 128; i++) s += Wcart[a*128+i]*Wcomp[i*128+j];
            W3[a*128+j] = s;
        }
        for (int sp = 0; sp < 4; sp++){
            float s1 = 0, s2 = 0;
            for (int i = 0; i < 128; i++){
                s1 += embc[sp*128+i]*Wcomp[(128+i)*128+j];
                s2 += embn[sp*128+i]*Wcomp[(256+i)*128+j];
            }
            ECn[sp*128+j] = s1; ENn[sp*128+j] = s2;
        }
    } else {                // init out with composition term (readout fused elsewhere)
        if (tid < N_STRUCT){
            float s = 0.f;
            for (int nl = 0; nl < PER; nl++){
                int z = numbers[tid*PER + nl];
                int el = (z==1)?0:(z==6)?1:(z==7)?2:3;
                s += cw[el];
            }
            out[tid] = s;
        }
    }
}

// ======= Persistent MFMA attention (pristine): weights in VGPRs, 35.6 KB LDS, 4 blocks/CU =======
__global__ __launch_bounds__(256, 2) void k_attn_p(float* __restrict__ X,
        const short* __restrict__ Wqt, const short* __restrict__ Wkt,
        const short* __restrict__ Wvt, const short* __restrict__ Wot,
        const float* __restrict__ lnw, const float* __restrict__ lnb,
        const float* __restrict__ radn){
    __shared__ short hh[32*136];    // LN out [t][j]
    __shared__ short Qs[32*136];    // Q[t][j]; aliased OB[t][j] after scores
    __shared__ short Ks[32*136];    // K[s][j]; head h's cols become P[t][s] after scores
    __shared__ short VT[128*40];    // V^T[j][s], mask folded
    __shared__ float radl[32];
    const int tid = threadIdx.x, lane = tid & 63, w = tid >> 6;
    const int quad = lane >> 4, l16 = lane & 15;

    bf16x8 wQ[8], wK[8], wV[8], wO[8];
    #pragma unroll
    for (int mt = 0; mt < 2; mt++)
        #pragma unroll
        for (int kk = 0; kk < 4; kk++){
            int ro = (w*32 + mt*16 + l16)*128 + kk*32 + quad*8;
            wQ[mt*4+kk] = *(const bf16x8*)&Wqt[ro];
            wK[mt*4+kk] = *(const bf16x8*)&Wkt[ro];
            wV[mt*4+kk] = *(const bf16x8*)&Wvt[ro];
            wO[mt*4+kk] = *(const bf16x8*)&Wot[ro];
        }

    for (int node = blockIdx.x; node < N_NODES; node += 1024){
        float* Xn = X + (size_t)node*4096;
        {   // LayerNorm from global -> hh; 8 threads/row
            int row = tid >> 3, l8 = tid & 7;
            f32x4 v[4];
            #pragma unroll
            for (int c = 0; c < 4; c++) v[c] = *(const f32x4*)&Xn[row*128 + l8*16 + c*4];
            float s = 0, ss = 0;
            #pragma unroll
            for (int c = 0; c < 4; c++){
                #pragma unroll
                for (int k = 0; k < 4; k++){ s += v[c][k]; ss += v[c][k]*v[c][k]; }
            }
            #pragma unroll
            for (int m = 1; m < 8; m <<= 1){ s += __shfl_xor(s, m); ss += __shfl_xor(ss, m); }
            float mean = s*(1.f/128.f);
            float rstd = rsqrtf(ss*(1.f/128.f) - mean*mean + 1e-5f);
            #pragma unroll
            for (int c = 0; c < 4; c++){
                f32x4 wv4 = *(const f32x4*)&lnw[l8*16 + c*4];
                f32x4 bv4 = *(const f32x4*)&lnb[l8*16 + c*4];
                short4 pk;
                pk.x = f2bf((v[c][0]-mean)*rstd*wv4[0] + bv4[0]);
                pk.y = f2bf((v[c][1]-mean)*rstd*wv4[1] + bv4[1]);
                pk.z = f2bf((v[c][2]-mean)*rstd*wv4[2] + bv4[2]);
                pk.w = f2bf((v[c][3]-mean)*rstd*wv4[3] + bv4[3]);
                *(short4*)&hh[row*136 + l8*16 + c*4] = pk;
            }
        }
        if (tid < 32) radl[tid] = radn[(size_t)node*32 + tid];
        __syncthreads();                     // (1)

        {   // Q+K pass
            f32x4 z = {0.f,0.f,0.f,0.f};
            f32x4 qacc[4] = {z,z,z,z}, kacc[4] = {z,z,z,z};
            #pragma unroll
            for (int kk = 0; kk < 4; kk++){
                bf16x8 h0 = *(const bf16x8*)&hh[(l16)*136    + kk*32 + quad*8];
                bf16x8 h1 = *(const bf16x8*)&hh[(16+l16)*136 + kk*32 + quad*8];
                #pragma unroll
                for (int mt = 0; mt < 2; mt++){
                    qacc[mt*2+0] = MFMA_B16(wQ[mt*4+kk], h0, qacc[mt*2+0]);
                    qacc[mt*2+1] = MFMA_B16(wQ[mt*4+kk], h1, qacc[mt*2+1]);
                    kacc[mt*2+0] = MFMA_B16(wK[mt*4+kk], h0, kacc[mt*2+0]);
                    kacc[mt*2+1] = MFMA_B16(wK[mt*4+kk], h1, kacc[mt*2+1]);
                }
            }
            #pragma unroll
            for (int mt = 0; mt < 2; mt++){
                #pragma unroll
                for (int nt = 0; nt < 2; nt++){
                    int t = nt*16 + l16, jb = w*32 + mt*16 + quad*4;
                    short4 pk;
                    pk.x = f2bf(qacc[mt*2+nt][0]); pk.y = f2bf(qacc[mt*2+nt][1]);
                    pk.z = f2bf(qacc[mt*2+nt][2]); pk.w = f2bf(qacc[mt*2+nt][3]);
                    *(short4*)&Qs[t*136 + jb] = pk;
                    short4 pk2;
                    pk2.x = f2bf(kacc[mt*2+nt][0]); pk2.y = f2bf(kacc[mt*2+nt][1]);
                    pk2.z = f2bf(kacc[mt*2+nt][2]); pk2.w = f2bf(kacc[mt*2+nt][3]);
                    *(short4*)&Ks[t*136 + jb] = pk2;
                }
            }
        }
        {   // V pass; rad folded
            f32x4 z = {0.f,0.f,0.f,0.f};
            f32x4 vacc[4] = {z,z,z,z};
            #pragma unroll
            for (int kk = 0; kk < 4; kk++){
                bf16x8 h0 = *(const bf16x8*)&hh[(l16)*136    + kk*32 + quad*8];
                bf16x8 h1 = *(const bf16x8*)&hh[(16+l16)*136 + kk*32 + quad*8];
                #pragma unroll
                for (int mt = 0; mt < 2; mt++){
                    vacc[0*2+mt] = MFMA_B16(h0, wV[mt*4+kk], vacc[0*2+mt]);
                    vacc[1*2+mt] = MFMA_B16(h1, wV[mt*4+kk], vacc[1*2+mt]);
                }
            }
            #pragma unroll
            for (int mt = 0; mt < 2; mt++){
                #pragma unroll
                for (int nt = 0; nt < 2; nt++){
                    int j = w*32 + nt*16 + l16, sb = mt*16 + quad*4;
                    f32x4 r4 = *(const f32x4*)&radl[sb];
                    short4 pk;
                    pk.x = f2bf(vacc[mt*2+nt][0]*r4[0]); pk.y = f2bf(vacc[mt*2+nt][1]*r4[1]);
                    pk.z = f2bf(vacc[mt*2+nt][2]*r4[2]); pk.w = f2bf(vacc[mt*2+nt][3]*r4[3]);
                    *(short4*)&VT[j*40 + sb] = pk;
                }
            }
        }
        {   // scores + softmax + P (into Ks own col block)
            const int h = w;
            bf16x8 qa0 = *(const bf16x8*)&Qs[(l16)*136    + h*32 + quad*8];
            bf16x8 qa1 = *(const bf16x8*)&Qs[(16+l16)*136 + h*32 + quad*8];
            bf16x8 kb0 = *(const bf16x8*)&Ks[(l16)*136    + h*32 + quad*8];
            bf16x8 kb1 = *(const bf16x8*)&Ks[(16+l16)*136 + h*32 + quad*8];
            f32x4 z = {0.f,0.f,0.f,0.f};
            f32x4 sc00 = MFMA_B16(qa0, kb0, z), sc01 = MFMA_B16(qa0, kb1, z);
            f32x4 sc10 = MFMA_B16(qa1, kb0, z), sc11 = MFMA_B16(qa1, kb1, z);
            #pragma unroll
            for (int mt = 0; mt < 2; mt++){
                f32x4 s0 = mt ? sc10 : sc00, s1 = mt ? sc11 : sc01;
                #pragma unroll
                for (int r = 0; r < 4; r++){
                    float mx = fmaxf(s0[r], s1[r]);
                    #pragma unroll
                    for (int dlt = 1; dlt < 16; dlt <<= 1) mx = fmaxf(mx, __shfl_xor(mx, dlt));
                    float e0 = __expf(s0[r]-mx), e1 = __expf(s1[r]-mx);
                    float sm = e0 + e1;
                    #pragma unroll
                    for (int dlt = 1; dlt < 16; dlt <<= 1) sm += __shfl_xor(sm, dlt);
                    float inv = __builtin_amdgcn_rcpf(sm);
                    int t = mt*16 + quad*4 + r;
                    Ks[t*136 + h*32 + l16]      = f2bf(e0*inv);
                    Ks[t*136 + h*32 + 16 + l16] = f2bf(e1*inv);
                }
            }
        }
        short* OB = Qs;
        {   // PV
            const int h = w;
            bf16x8 pa0 = *(const bf16x8*)&Ks[(l16)*136    + h*32 + quad*8];
            bf16x8 pa1 = *(const bf16x8*)&Ks[(16+l16)*136 + h*32 + quad*8];
            bf16x8 vb0 = *(const bf16x8*)&VT[(h*32 + l16)*40      + quad*8];
            bf16x8 vb1 = *(const bf16x8*)&VT[(h*32 + 16 + l16)*40 + quad*8];
            f32x4 z = {0.f,0.f,0.f,0.f};
            f32x4 o00 = MFMA_B16(pa0, vb0, z), o01 = MFMA_B16(pa0, vb1, z);
            f32x4 o10 = MFMA_B16(pa1, vb0, z), o11 = MFMA_B16(pa1, vb1, z);
            #pragma unroll
            for (int mt = 0; mt < 2; mt++){
                #pragma unroll
                for (int nt = 0; nt < 2; nt++){
                    f32x4 ov = mt ? (nt ? o11 : o10) : (nt ? o01 : o00);
                    int j = w*32 + nt*16 + l16;
                    #pragma unroll
                    for (int r = 0; r < 4; r++){
                        int t = mt*16 + quad*4 + r;
                        OB[t*136 + j] = f2bf(ov[r]);
                    }
                }
            }
        }
        __syncthreads();                     // (2)
        {   // O-projection + residual RMW -> global
            f32x4 z = {0.f,0.f,0.f,0.f};
            f32x4 oc[4] = {z,z,z,z};
            #pragma unroll
            for (int kk = 0; kk < 4; kk++){
                bf16x8 a0 = *(const bf16x8*)&OB[(l16)*136    + kk*32 + quad*8];
                bf16x8 a1 = *(const bf16x8*)&OB[(16+l16)*136 + kk*32 + quad*8];
                #pragma unroll
                for (int nt = 0; nt < 2; nt++){
                    oc[0+nt] = MFMA_B16(a0, wO[nt*4+kk], oc[0+nt]);
                    oc[2+nt] = MFMA_B16(a1, wO[nt*4+kk], oc[2+nt]);
                }
            }
            #pragma unroll
            for (int mt = 0; mt < 2; mt++){
                #pragma unroll
                for (int nt = 0; nt < 2; nt++){
                    int j2 = w*32 + nt*16 + l16;
                    #pragma unroll
                    for (int r = 0; r < 4; r++){
                        int t = mt*16 + quad*4 + r;
                        Xn[t*128 + j2] += oc[mt*2+nt][r];
                    }
                }
            }
        }
    }
}

// ======= Attention clone with fused encoder (mode 1) / PADV pad-source (mode 2) =======
// mode 1 (t-stack l0): computes encoder X in the LN stage, stores X + RADN.
// mode 2 (g-stack l0): pad rows (s>=24) sourced from PADV (contract's edge-0 value)
//                      and stored to Y so the epilogue RMW is valid.
__global__ __launch_bounds__(256, 2) void k_attn_x(float* __restrict__ X,
        const short* __restrict__ Wqt, const short* __restrict__ Wkt,
        const short* __restrict__ Wvt, const short* __restrict__ Wot,
        const float* __restrict__ lnw, const float* __restrict__ lnb,
        float* __restrict__ RADN, const float* __restrict__ RAD,
        const int* __restrict__ centers, const int* __restrict__ neighbors,
        const int* __restrict__ ELEM, const float* __restrict__ EV,
        const float* __restrict__ W3, const float* __restrict__ ECn,
        const float* __restrict__ ENn, const float* __restrict__ PADV,
        const int mode){
    __shared__ short hh[32*136];
    __shared__ short Qs[32*136];
    __shared__ short Ks[32*136];
    __shared__ short VT[128*40];
    __shared__ float radl[32];
    const int tid = threadIdx.x, lane = tid & 63, w = tid >> 6;
    const int quad = lane >> 4, l16 = lane & 15;

    bf16x8 wQ[8], wK[8], wV[8], wO[8];
    #pragma unroll
    for (int mt = 0; mt < 2; mt++)
        #pragma unroll
        for (int kk = 0; kk < 4; kk++){
            int ro = (w*32 + mt*16 + l16)*128 + kk*32 + quad*8;
            wQ[mt*4+kk] = *(const bf16x8*)&Wqt[ro];
            wK[mt*4+kk] = *(const bf16x8*)&Wkt[ro];
            wV[mt*4+kk] = *(const bf16x8*)&Wvt[ro];
            wO[mt*4+kk] = *(const bf16x8*)&Wot[ro];
        }

    for (int node = blockIdx.x; node < N_NODES; node += 1024){
        float* Xn = X + (size_t)node*4096;
        {   // stage 1: produce v[4] per (row, l8), store X where needed, LN -> hh
            int row = tid >> 3, l8 = tid & 7;
            f32x4 v[4];
            if (mode == 1){
                int e = (row < K_NB) ? (node*K_NB + row) : 0;
                int ec = ELEM[centers[e]], en = ELEM[neighbors[e]];
                float ev0 = EV[e*3+0], ev1 = EV[e*3+1], ev2 = EV[e*3+2];
                #pragma unroll
                for (int c = 0; c < 4; c++){
                    int j = l8*16 + c*4;
                    f32x4 wa = *(const f32x4*)&W3[j];
                    f32x4 wb = *(const f32x4*)&W3[128+j];
                    f32x4 wc = *(const f32x4*)&W3[256+j];
                    f32x4 ea = *(const f32x4*)&ECn[ec*128+j];
                    f32x4 na = *(const f32x4*)&ENn[en*128+j];
                    #pragma unroll
                    for (int k = 0; k < 4; k++)
                        v[c][k] = ev0*wa[k] + ev1*wb[k] + ev2*wc[k] + ea[k] + na[k];
                    *(f32x4*)&Xn[row*128 + j] = v[c];
                }
                if (tid < 32){
                    float rr = (tid < K_NB) ? RAD[node*K_NB + tid] : 0.f;
                    radl[tid] = rr;
                    RADN[(size_t)node*32 + tid] = rr;
                }
            } else { // mode 2
                const float* src = (row >= K_NB) ? PADV : (Xn + row*128);
                #pragma unroll
                for (int c = 0; c < 4; c++) v[c] = *(const f32x4*)&src[l8*16 + c*4];
                if (row >= K_NB){
                    #pragma unroll
                    for (int c = 0; c < 4; c++) *(f32x4*)&Xn[row*128 + l8*16 + c*4] = v[c];
                }
                if (tid < 32) radl[tid] = RADN[(size_t)node*32 + tid];
            }
            float s = 0, ss = 0;
            #pragma unroll
            for (int c = 0; c < 4; c++){
                #pragma unroll
                for (int k = 0; k < 4; k++){ s += v[c][k]; ss += v[c][k]*v[c][k]; }
            }
            #pragma unroll
            for (int m = 1; m < 8; m <<= 1){ s += __shfl_xor(s, m); ss += __shfl_xor(ss, m); }
            float mean = s*(1.f/128.f);
            float rstd = rsqrtf(ss*(1.f/128.f) - mean*mean + 1e-5f);
            #pragma unroll
            for (int c = 0; c < 4; c++){
                f32x4 wv4 = *(const f32x4*)&lnw[l8*16 + c*4];
                f32x4 bv4 = *(const f32x4*)&lnb[l8*16 + c*4];
                short4 pk;
                pk.x = f2bf((v[c][0]-mean)*rstd*wv4[0] + bv4[0]);
                pk.y = f2bf((v[c][1]-mean)*rstd*wv4[1] + bv4[1]);
                pk.z = f2bf((v[c][2]-mean)*rstd*wv4[2] + bv4[2]);
                pk.w = f2bf((v[c][3]-mean)*rstd*wv4[3] + bv4[3]);
                *(short4*)&hh[row*136 + l8*16 + c*4] = pk;
            }
        }
        __syncthreads();                     // (1) hh/radl + X stores visible

        {   // Q+K pass
            f32x4 z = {0.f,0.f,0.f,0.f};
            f32x4 qacc[4] = {z,z,z,z}, kacc[4] = {z,z,z,z};
            #pragma unroll
            for (int kk = 0; kk < 4; kk++){
                bf16x8 h0 = *(const bf16x8*)&hh[(l16)*136    + kk*32 + quad*8];
                bf16x8 h1 = *(const bf16x8*)&hh[(16+l16)*136 + kk*32 + quad*8];
                #pragma unroll
                for (int mt = 0; mt < 2; mt++){
                    qacc[mt*2+0] = MFMA_B16(wQ[mt*4+kk], h0, qacc[mt*2+0]);
                    qacc[mt*2+1] = MFMA_B16(wQ[mt*4+kk], h1, qacc[mt*2+1]);
                    kacc[mt*2+0] = MFMA_B16(wK[mt*4+kk], h0, kacc[mt*2+0]);
                    kacc[mt*2+1] = MFMA_B16(wK[mt*4+kk], h1, kacc[mt*2+1]);
                }
            }
            #pragma unroll
            for (int mt = 0; mt < 2; mt++){
                #pragma unroll
                for (int nt = 0; nt < 2; nt++){
                    int t = nt*16 + l16, jb = w*32 + mt*16 + quad*4;
                    short4 pk;
                    pk.x = f2bf(qacc[mt*2+nt][0]); pk.y = f2bf(qacc[mt*2+nt][1]);
                    pk.z = f2bf(qacc[mt*2+nt][2]); pk.w = f2bf(qacc[mt*2+nt][3]);
                    *(short4*)&Qs[t*136 + jb] = pk;
                    short4 pk2;
                    pk2.x = f2bf(kacc[mt*2+nt][0]); pk2.y = f2bf(kacc[mt*2+nt][1]);
                    pk2.z = f2bf(kacc[mt*2+nt][2]); pk2.w = f2bf(kacc[mt*2+nt][3]);
                    *(short4*)&Ks[t*136 + jb] = pk2;
                }
            }
        }
        {   // V pass; rad folded
            f32x4 z = {0.f,0.f,0.f,0.f};
            f32x4 vacc[4] = {z,z,z,z};
            #pragma unroll
            for (int kk = 0; kk < 4; kk++){
                bf16x8 h0 = *(const bf16x8*)&hh[(l16)*136    + kk*32 + quad*8];
                bf16x8 h1 = *(const bf16x8*)&hh[(16+l16)*136 + kk*32 + quad*8];
                #pragma unroll
                for (int mt = 0; mt < 2; mt++){
                    vacc[0*2+mt] = MFMA_B16(h0, wV[mt*4+kk], vacc[0*2+mt]);
                    vacc[1*2+mt] = MFMA_B16(h1, wV[mt*4+kk], vacc[1*2+mt]);
                }
            }
            #pragma unroll
            for (int mt = 0; mt < 2; mt++){
                #pragma unroll
                for (int nt = 0; nt < 2; nt++){
                    int j = w*32 + nt*16 + l16, sb = mt*16 + quad*4;
                    f32x4 r4 = *(const f32x4*)&radl[sb];
                    short4 pk;
                    pk.x = f2bf(vacc[mt*2+nt][0]*r4[0]); pk.y = f2bf(vacc[mt*2+nt][1]*r4[1]);
                    pk.z = f2bf(vacc[mt*2+nt][2]*r4[2]); pk.w = f2bf(vacc[mt*2+nt][3]*r4[3]);
                    *(short4*)&VT[j*40 + sb] = pk;
                }
            }
        }
        {   // scores + softmax + P
            const int h = w;
            bf16x8 qa0 = *(const bf16x8*)&Qs[(l16)*136    + h*32 + quad*8];
            bf16x8 qa1 = *(const bf16x8*)&Qs[(16+l16)*136 + h*32 + quad*8];
            bf16x8 kb0 = *(const bf16x8*)&Ks[(l16)*136    + h*32 + quad*8];
            bf16x8 kb1 = *(const bf16x8*)&Ks[(16+l16)*136 + h*32 + quad*8];
            f32x4 z = {0.f,0.f,0.f,0.f};
            f32x4 sc00 = MFMA_B16(qa0, kb0, z), sc01 = MFMA_B16(qa0, kb1, z);
            f32x4 sc10 = MFMA_B16(qa1, kb0, z), sc11 = MFMA_B16(qa1, kb1, z);
            #pragma unroll
            for (int mt = 0; mt < 2; mt++){
                f32x4 s0 = mt ? sc10 : sc00, s1 = mt ? sc11 : sc01;
                #pragma unroll
                for (int r = 0; r < 4; r++){
                    float mx = fmaxf(s0[r], s1[r]);
                    #pragma unroll
                    for (int dlt = 1; dlt < 16; dlt <<= 1) mx = fmaxf(mx, __shfl_xor(mx, dlt));
                    float e0 = __expf(s0[r]-mx), e1 = __expf(s1[r]-mx);
                    float sm = e0 + e1;
                    #pragma unroll
                    for (int dlt = 1; dlt < 16; dlt <<= 1) sm += __shfl_xor(sm, dlt);
                    float inv = __builtin_amdgcn_rcpf(sm);
                    int t = mt*16 + quad*4 + r;
                    Ks[t*136 + h*32 + l16]      = f2bf(e0*inv);
                    Ks[t*136 + h*32 + 16 + l16] = f2bf(e1*inv);
                }
            }
        }
        short* OB = Qs;
        {   // PV
            const int h = w;
            bf16x8 pa0 = *(const bf16x8*)&Ks[(l16)*136    + h*32 + quad*8];
            bf16x8 pa1 = *(const bf16x8*)&Ks[(16+l16)*136 + h*32 + quad*8];
            bf16x8 vb0 = *(const bf16x8*)&VT[(h*32 + l16)*40      + quad*8];
            bf16x8 vb1 = *(const bf16x8*)&VT[(h*32 + 16 + l16)*40 + quad*8];
            f32x4 z = {0.f,0.f,0.f,0.f};
            f32x4 o00 = MFMA_B16(pa0, vb0, z), o01 = MFMA_B16(pa0, vb1, z);
            f32x4 o10 = MFMA_B16(pa1, vb0, z), o11 = MFMA_B16(pa1, vb1, z);
            #pragma unroll
            for (int mt = 0; mt < 2; mt++){
                #pragma unroll
                for (int nt = 0; nt < 2; nt++){
                    f32x4 ov = mt ? (nt ? o11 : o10) : (nt ? o01 : o00);
                    int j = w*32 + nt*16 + l16;
                    #pragma unroll
                    for (int r = 0; r < 4; r++){
                        int t = mt*16 + quad*4 + r;
                        OB[t*136 + j] = f2bf(ov[r]);
                    }
                }
            }
        }
        __syncthreads();                     // (2)
        {   // O-projection + residual RMW
            f32x4 z = {0.f,0.f,0.f,0.f};
            f32x4 oc[4] = {z,z,z,z};
            #pragma unroll
            for (int kk = 0; kk < 4; kk++){
                bf16x8 a0 = *(const bf16x8*)&OB[(l16)*136    + kk*32 + quad*8];
                bf16x8 a1 = *(const bf16x8*)&OB[(16+l16)*136 + kk*32 + quad*8];
                #pragma unroll
                for (int nt = 0; nt < 2; nt++){
                    oc[0+nt] = MFMA_B16(a0, wO[nt*4+kk], oc[0+nt]);
                    oc[2+nt] = MFMA_B16(a1, wO[nt*4+kk], oc[2+nt]);
                }
            }
            #pragma unroll
            for (int mt = 0; mt < 2; mt++){
                #pragma unroll
                for (int nt = 0; nt < 2; nt++){
                    int j2 = w*32 + nt*16 + l16;
                    #pragma unroll
                    for (int r = 0; r < 4; r++){
                        int t = mt*16 + quad*4 + r;
                        Xn[t*128 + j2] += oc[mt*2+nt][r];
                    }
                }
            }
        }
    }
}

// ======= Persistent MFMA FFN (xs residual, 3 barriers); optional fused Y-readout =======
__global__ __launch_bounds__(512, 2) void k_ffn_p(float* __restrict__ X,
        const short* __restrict__ W1t, const short* __restrict__ W2t,
        const float* __restrict__ B1, const float* __restrict__ B2,
        const float* __restrict__ lnw, const float* __restrict__ lnb,
        const float* __restrict__ rW, const float* __restrict__ radn,
        float* __restrict__ out){
    __shared__ float xs[32*132];     // fp32 residual
    __shared__ short hh[32*136];     // LN out bf16
    __shared__ short mid[32*520];    // gelu out bf16
    __shared__ float radl2[32];
    __shared__ float wsumR[8];
    const int tid = threadIdx.x, lane = tid & 63, w = tid >> 6;
    const int quad = lane >> 4, l16 = lane & 15;

    bf16x8 wA[16];
    #pragma unroll
    for (int mt = 0; mt < 4; mt++)
        #pragma unroll
        for (int kk = 0; kk < 4; kk++)
            wA[mt*4+kk] = *(const bf16x8*)&W1t[(size_t)(w*64+mt*16+l16)*128 + kk*32 + quad*8];
    bf16x8 wB[16];
    #pragma unroll
    for (int kk = 0; kk < 16; kk++)
        wB[kk] = *(const bf16x8*)&W2t[(size_t)(w*16+l16)*512 + kk*32 + quad*8];
    f32x4 bb1[4];
    #pragma unroll
    for (int mt = 0; mt < 4; mt++) bb1[mt] = *(const f32x4*)&B1[w*64 + mt*16 + quad*4];
    const float b2v = B2[w*16 + l16];
    const float rwv = rW ? rW[w*16 + l16] : 0.f;

    for (int tile = blockIdx.x; tile < NTOK/32; tile += 512){
        float* Xg = X + (size_t)tile*4096;
        {   // load + LN: 16 threads/row, 8 floats each
            int row = tid >> 4, lc = tid & 15;
            f32x4 v0 = *(const f32x4*)&Xg[row*128 + lc*8];
            f32x4 v1 = *(const f32x4*)&Xg[row*128 + lc*8 + 4];
            *(f32x4*)&xs[row*132 + lc*8]     = v0;
            *(f32x4*)&xs[row*132 + lc*8 + 4] = v1;
            float s = 0, ss = 0;
            #pragma unroll
            for (int k = 0; k < 4; k++){ s += v0[k]+v1[k]; ss += v0[k]*v0[k]+v1[k]*v1[k]; }
            #pragma unroll
            for (int m = 1; m < 16; m <<= 1){ s += __shfl_xor(s, m); ss += __shfl_xor(ss, m); }
            float mean = s*(1.f/128.f);
            float rstd = rsqrtf(ss*(1.f/128.f) - mean*mean + 1e-5f);
            f32x4 w0 = *(const f32x4*)&lnw[lc*8], w1 = *(const f32x4*)&lnw[lc*8+4];
            f32x4 g0 = *(const f32x4*)&lnb[lc*8], g1 = *(const f32x4*)&lnb[lc*8+4];
            short4 pa, pb;
            pa.x = f2bf((v0[0]-mean)*rstd*w0[0] + g0[0]);
            pa.y = f2bf((v0[1]-mean)*rstd*w0[1] + g0[1]);
            pa.z = f2bf((v0[2]-mean)*rstd*w0[2] + g0[2]);
            pa.w = f2bf((v0[3]-mean)*rstd*w0[3] + g0[3]);
            pb.x = f2bf((v1[0]-mean)*rstd*w1[0] + g1[0]);
            pb.y = f2bf((v1[1]-mean)*rstd*w1[1] + g1[1]);
            pb.z = f2bf((v1[2]-mean)*rstd*w1[2] + g1[2]);
            pb.w = f2bf((v1[3]-mean)*rstd*w1[3] + g1[3]);
            *(short4*)&hh[row*136 + lc*8]     = pa;
            *(short4*)&hh[row*136 + lc*8 + 4] = pb;
        }
        if (rW && tid < 32) radl2[tid] = radn[(size_t)tile*32 + tid];
        __syncthreads();
        {   // FFN1
            f32x4 z = {0.f,0.f,0.f,0.f};
            f32x4 acc[8];
            #pragma unroll
            for (int i = 0; i < 8; i++) acc[i] = z;
            #pragma unroll
            for (int kk = 0; kk < 4; kk++){
                bf16x8 h0 = *(const bf16x8*)&hh[(l16)*136    + kk*32 + quad*8];
                bf16x8 h1 = *(const bf16x8*)&hh[(16+l16)*136 + kk*32 + quad*8];
                #pragma unroll
                for (int mt = 0; mt < 4; mt++){
                    acc[mt*2+0] = MFMA_B16(wA[mt*4+kk], h0, acc[mt*2+0]);
                    acc[mt*2+1] = MFMA_B16(wA[mt*4+kk], h1, acc[mt*2+1]);
                }
            }
            #pragma unroll
            for (int mt = 0; mt < 4; mt++){
                int fb = w*64 + mt*16 + quad*4;
                #pragma unroll
                for (int nt = 0; nt < 2; nt++){
                    int t = nt*16 + l16;
                    short4 pk;
                    pk.x = f2bf(gelu_f(acc[mt*2+nt][0] + bb1[mt][0]));
                    pk.y = f2bf(gelu_f(acc[mt*2+nt][1] + bb1[mt][1]));
                    pk.z = f2bf(gelu_f(acc[mt*2+nt][2] + bb1[mt][2]));
                    pk.w = f2bf(gelu_f(acc[mt*2+nt][3] + bb1[mt][3]));
                    *(short4*)&mid[t*520 + fb] = pk;
                }
            }
        }
        __syncthreads();
        {   // FFN2 + residual / fused Y-readout
            f32x4 z = {0.f,0.f,0.f,0.f};
            f32x4 o0 = z, o1 = z;
            #pragma unroll
            for (int kk = 0; kk < 16; kk++){
                bf16x8 a0 = *(const bf16x8*)&mid[(l16)*520    + kk*32 + quad*8];
                bf16x8 a1 = *(const bf16x8*)&mid[(16+l16)*520 + kk*32 + quad*8];
                o0 = MFMA_B16(a0, wB[kk], o0);
                o1 = MFMA_B16(a1, wB[kk], o1);
            }
            int j = w*16 + l16;
            if (!rW){
                #pragma unroll
                for (int r = 0; r < 4; r++){
                    int t0 = quad*4 + r, t1 = 16 + quad*4 + r;
                    Xg[t0*128 + j] = xs[t0*132 + j] + o0[r] + b2v;
                    Xg[t1*128 + j] = xs[t1*132 + j] + o1[r] + b2v;
                }
            } else {
                float part = 0.f;
                #pragma unroll
                for (int r = 0; r < 4; r++){
                    int t0 = quad*4 + r, t1 = 16 + quad*4 + r;
                    float y0 = xs[t0*132 + j] + o0[r] + b2v;
                    float y1 = xs[t1*132 + j] + o1[r] + b2v;
                    part += y0 * radl2[t0] + y1 * radl2[t1];
                }
                part *= rwv;
                #pragma unroll
                for (int m = 1; m < 64; m <<= 1) part += __shfl_xor(part, m);
                if (lane == 0) wsumR[w] = part;
            }
        }
        __syncthreads();
        if (rW && tid == 0){
            float tot = 0.f;
            #pragma unroll
            for (int i = 0; i < 8; i++) tot += wsumR[i];
            atomicAdd(&out[tile/PER], tot);
        }
    }
}

// ---- MFMA edge contraction: 32 edges/block; X-readout accumulation; PADV stash ----
__global__ __launch_bounds__(256) void k_contract_mfma(const float* __restrict__ X,
        const int* __restrict__ centers, const int* __restrict__ CORR,
        const short* __restrict__ gct, float* __restrict__ Y,
        const float* __restrict__ rW, const float* __restrict__ RADN,
        float* __restrict__ out, float* __restrict__ PADV){
    __shared__ short ab[32*264];    // [edge][256 concat feats]
    __shared__ float red[4];
    const int tid = threadIdx.x, lane = tid & 63, w = tid >> 6;
    const int quad = lane >> 4, l16 = lane & 15;
    const int e0 = blockIdx.x*32;
    float px = 0.f;
    for (int idx = tid; idx < 2048; idx += 256){
        int r = idx >> 6, c4 = idx & 63;
        int e = e0 + r, srcRow;
        bool own = (c4 < 32);
        if (own){ int c = centers[e]; srcRow = c*32 + (e - c*K_NB); }
        else    { int ec = CORR[e]; int c = centers[ec]; srcRow = c*32 + (ec - c*K_NB); }
        float4 v = *(const float4*)&X[(size_t)srcRow*128 + (c4 & 31)*4];
        if (own){
            float4 rw4 = *(const float4*)&rW[(c4 & 31)*4];
            px += (v.x*rw4.x + v.y*rw4.y + v.z*rw4.z + v.w*rw4.w) * RADN[srcRow];
        }
        short4 pk; pk.x = f2bf(v.x); pk.y = f2bf(v.y); pk.z = f2bf(v.z); pk.w = f2bf(v.w);
        *(short4*)&ab[r*264 + c4*4] = pk;
    }
    #pragma unroll
    for (int m = 1; m < 64; m <<= 1) px += __shfl_xor(px, m);
    if (lane == 0) red[w] = px;
    __syncthreads();
    if (tid == 0) atomicAdd(&out[blockIdx.x/75], red[0]+red[1]+red[2]+red[3]);
    f32x4 z = {0.f,0.f,0.f,0.f};
    f32x4 o[4] = {z,z,z,z};
    #pragma unroll
    for (int kk = 0; kk < 8; kk++){
        bf16x8 a0 = *(const bf16x8*)&ab[(l16)*264    + kk*32 + quad*8];
        bf16x8 a1 = *(const bf16x8*)&ab[(16+l16)*264 + kk*32 + quad*8];
        #pragma unroll
        for (int nt = 0; nt < 2; nt++){
            bf16x8 bw = *(const bf16x8*)&gct[(size_t)(w*32+nt*16+l16)*256 + kk*32 + quad*8];
            o[0+nt] = MFMA_B16(a0, bw, o[0+nt]);
            o[2+nt] = MFMA_B16(a1, bw, o[2+nt]);
        }
    }
    #pragma unroll
    for (int mt = 0; mt < 2; mt++){
        #pragma unroll
        for (int nt = 0; nt < 2; nt++){
            int j = w*32 + nt*16 + l16;
            #pragma unroll
            for (int r = 0; r < 4; r++){
                int e = e0 + mt*16 + quad*4 + r;
                int c = e / K_NB, slot = e - c*K_NB;
                Y[((size_t)c*32 + slot)*128 + j] = o[mt*2+nt][r];
                if (blockIdx.x == 0 && mt == 0 && quad == 0 && r == 0)
                    PADV[j] = o[mt*2+nt][r];   // edge 0's contracted value (pad source)
            }
        }
    }
}

extern "C" void kernel_launch(void* const* d_in, const int* in_sizes, int n_in,
                              void* d_out, int out_size, void* d_ws, size_t ws_size,
                              hipStream_t stream){
    const float* positions   = (const float*)d_in[0];
    const float* cells       = (const float*)d_in[1];
    const float* cell_shifts = (const float*)d_in[2];
    const float* enc_Wcart   = (const float*)d_in[3];
    const float* enc_emb_c   = (const float*)d_in[4];
    const float* enc_emb_n   = (const float*)d_in[5];
    const float* enc_Wcomp   = (const float*)d_in[6];
    const float* t_Wq  = (const float*)d_in[7];
    const float* t_Wk  = (const float*)d_in[8];
    const float* t_Wv  = (const float*)d_in[9];
    const float* t_Wo  = (const float*)d_in[10];
    const float* t_ln1w = (const float*)d_in[11];
    const float* t_ln1b = (const float*)d_in[12];
    const float* t_ln2w = (const float*)d_in[13];
    const float* t_ln2b = (const float*)d_in[14];
    const float* t_W1  = (const float*)d_in[15];
    const float* t_b1  = (const float*)d_in[16];
    const float* t_W2  = (const float*)d_in[17];
    const float* t_b2  = (const float*)d_in[18];
    const float* g_contr = (const float*)d_in[19];
    const float* g_Wq  = (const float*)d_in[20];
    const float* g_Wk  = (const float*)d_in[21];
    const float* g_Wv  = (const float*)d_in[22];
    const float* g_Wo  = (const float*)d_in[23];
    const float* g_ln1w = (const float*)d_in[24];
    const float* g_ln1b = (const float*)d_in[25];
    const float* g_ln2w = (const float*)d_in[26];
    const float* g_ln2b = (const float*)d_in[27];
    const float* g_W1  = (const float*)d_in[28];
    const float* g_b1  = (const float*)d_in[29];
    const float* g_W2  = (const float*)d_in[30];
    const float* g_b2  = (const float*)d_in[31];
    const float* readout_W = (const float*)d_in[32];
    const float* comp_w    = (const float*)d_in[33];
    const int* numbers   = (const int*)d_in[34];
    const int* centers   = (const int*)d_in[35];
    const int* neighbors = (const int*)d_in[36];

    float* ws = (float*)d_ws;
    float* X    = ws;                       // NTOK*D
    float* Y    = X + (size_t)NTOK*D;       // NTOK*D
    float* EV   = Y + (size_t)NTOK*D;       // N_EDGES*3
    float* RAD  = EV + (size_t)N_EDGES*3;   // N_EDGES
    float* RADN = RAD + N_EDGES;            // NTOK
    float* W3   = RADN + NTOK;              // 3*128
    float* ECn  = W3 + 3*128;               // 4*128
    float* ENn  = ECn + 4*128;              // 4*128
    int*   ELEM = (int*)(ENn + 4*128);      // N_NODES
    int*   CORR = ELEM + N_NODES;           // N_EDGES
    short* WT   = (short*)(CORR + N_EDGES); // 819200 bf16 elems
    float* PADV = (float*)(WT + 819200);    // 128 floats

    const short *tWqt = WT,           *tWkt = WT + 32768, *tWvt = WT + 65536, *tWot = WT + 98304;
    const short *tW1t = WT + 131072,  *tW2t = WT + 262144;
    const short *gWqt = WT + 393216,  *gWkt = WT + 425984, *gWvt = WT + 458752, *gWot = WT + 491520;
    const short *gW1t = WT + 524288,  *gW2t = WT + 655360, *gctT = WT + 786432;

    k_setup<<<3691, 256, 0, stream>>>(t_Wq, t_Wk, t_Wv, t_Wo, t_W1, t_W2,
                                      g_Wq, g_Wk, g_Wv, g_Wo, g_W1, g_W2, g_contr, WT,
                                      positions, cells, cell_shifts, centers, neighbors,
                                      EV, RAD, CORR, numbers, ELEM,
                                      enc_Wcart, enc_emb_c, enc_emb_n, enc_Wcomp,
                                      W3, ECn, ENn, comp_w, (float*)d_out);

    // t-stack: l0 attention with fused encoder
    k_attn_x<<<1024, 256, 0, stream>>>(X, tWqt, tWkt, tWvt, tWot,
                                       t_ln1w, t_ln1b, RADN, RAD,
                                       centers, neighbors, ELEM, EV, W3, ECn, ENn,
                                       PADV, 1);
    k_ffn_p<<<512, 512, 0, stream>>>(X, tW1t, tW2t, t_b1, t_b2,
                                     t_ln2w, t_ln2b, nullptr, nullptr, nullptr);
    k_attn_p<<<1024, 256, 0, stream>>>(X, tWqt + 16384, tWkt + 16384,
                                       tWvt + 16384, tWot + 16384,
                                       t_ln1w + 128, t_ln1b + 128, RADN);
    k_ffn_p<<<512, 512, 0, stream>>>(X, tW1t + 65536, tW2t + 65536,
                                     t_b1 + 512, t_b2 + 128,
                                     t_ln2w + 128, t_ln2b + 128, nullptr, nullptr, nullptr);

    // contract: X readout accumulation + PADV stash
    k_contract_mfma<<<N_EDGES/32, 256, 0, stream>>>(X, centers, CORR, gctT, Y,
                                                    readout_W, RADN, (float*)d_out, PADV);

    // g-stack: l0 attention with PADV pad-source (replaces padfill)
    k_attn_x<<<1024, 256, 0, stream>>>(Y, gWqt, gWkt, gWvt, gWot,
                                       g_ln1w, g_ln1b, RADN, RAD,
                                       centers, neighbors, ELEM, EV, W3, ECn, ENn,
                                       PADV, 2);
    k_ffn_p<<<512, 512, 0, stream>>>(Y, gW1t, gW2t, g_b1, g_b2,
                                     g_ln2w, g_ln2b, nullptr, nullptr, nullptr);
    k_attn_p<<<1024, 256, 0, stream>>>(Y, gWqt + 16384, gWkt + 16384,
                                       gWvt + 16384, gWot + 16384,
                                       g_ln1w + 128, g_ln1b + 128, RADN);
    k_ffn_p<<<512, 512, 0, stream>>>(Y, gW1t + 65536, gW2t + 65536,
                                     g_b1 + 512, g_b2 + 128,
                                     g_ln2w + 128, g_ln2b + 128,
                                     readout_W, RADN, (float*)d_out);
}

// Round 16
// 951.397 us; speedup vs baseline: 1.0422x; 1.0422x over previous
//
#include <hip/hip_runtime.h>
#include <hip/hip_bf16.h>
#include <math.h>

#define N_NODES 5000
#define N_STRUCT 50
#define PER 100
#define K_NB 24
#define N_EDGES (N_NODES*K_NB)
#define TMAX 32
#define D 128
#define FF 512
#define NTOK (N_NODES*TMAX)

typedef short bf16x8 __attribute__((ext_vector_type(8)));
typedef float f32x4  __attribute__((ext_vector_type(4)));
#define MFMA_B16(a,b,c) __builtin_amdgcn_mfma_f32_16x16x32_bf16(a,b,c,0,0,0)

__device__ __forceinline__ short f2bf(float x){           // round-half-up float->bf16 (2 ops)
    return (short)((__float_as_uint(x) + 0x8000u) >> 16);
}
__device__ __forceinline__ short f2bf_rn(float x){        // RTNE (weights only)
    unsigned u = __float_as_uint(x);
    return (short)((u + 0x7FFFu + ((u>>16)&1u)) >> 16);
}

__device__ __forceinline__ float gelu_f(float x){
    // x*sigmoid(2u) == 0.5x(1+tanh(u)); 1 exp + 1 rcp
    float arg = x * fmaf(x*x, -0.07135481627f, -1.5957691216057308f);  // -2u
    return x * __builtin_amdgcn_rcpf(1.f + __expf(arg));
}

__device__ __forceinline__ float cutoff_f(float r){
    if (r < 3.f) return 1.f;
    if (r >= 5.f) return 0.f;
    float x = (r-3.f)*0.5f;
    return 0.5f*(1.f + cosf(3.14159265358979323846f * x));
}

// === Merged setup: [0,3200) wt | [3200,3669) edge | [3669,3689) elem | 3689 prep | 3690 comp-init
__global__ void k_setup(const float* tWq, const float* tWk, const float* tWv, const float* tWo,
                        const float* tW1, const float* tW2, const float* gWq, const float* gWk,
                        const float* gWv, const float* gWo, const float* gW1, const float* gW2,
                        const float* gct, short* __restrict__ WT,
                        const float* __restrict__ pos, const float* __restrict__ cells,
                        const float* __restrict__ shifts, const int* __restrict__ centers,
                        const int* __restrict__ neighbors, float* __restrict__ EV,
                        float* __restrict__ RAD, int* __restrict__ CORR,
                        const int* __restrict__ numbers, int* __restrict__ ELEM,
                        const float* __restrict__ Wcart, const float* __restrict__ embc,
                        const float* __restrict__ embn, const float* __restrict__ Wcomp,
                        float* __restrict__ W3, float* __restrict__ ECn, float* __restrict__ ENn,
                        const float* __restrict__ cw, float* __restrict__ out){
    int b = blockIdx.x, tid = threadIdx.x;
    if (b < 3200){   // weight transpose+bf16; Wq gets 1/sqrt(32) folded
        const int  sel[25]  = {0,0,1,1,2,2,3,3,4,4,5,5,6,6,7,7,8,8,9,9,10,10,11,11,12};
        const int  lin[25]  = {7,7,7,7,7,7,7,7,7,7,9,9,7,7,7,7,7,7,7,7,7,7,9,9,8};
        const int  lout[25] = {7,7,7,7,7,7,7,7,9,9,7,7,7,7,7,7,7,7,7,7,9,9,7,7,7};
        const int  soff[25] = {0,16384,0,16384,0,16384,0,16384,0,65536,0,65536,
                               0,16384,0,16384,0,16384,0,16384,0,65536,0,65536,0};
        const int  doff[25] = {0,16384,32768,49152,65536,81920,98304,114688,
                               131072,196608,262144,327680,
                               393216,409600,425984,442368,458752,475136,491520,507904,
                               524288,589824,655360,720896,786432};
        int gid = b*256 + tid;
        int r = 0, base = 0;
        while (true){
            int sz = 1 << (lin[r]+lout[r]);
            if (gid < base + sz) break;
            base += sz; r++;
        }
        int d = gid - base;
        int j = d >> lin[r], i = d & ((1<<lin[r])-1);
        const float* src;
        switch (sel[r]){
            case 0: src=tWq; break; case 1: src=tWk; break; case 2: src=tWv; break; case 3: src=tWo; break;
            case 4: src=tW1; break; case 5: src=tW2; break;
            case 6: src=gWq; break; case 7: src=gWk; break; case 8: src=gWv; break; case 9: src=gWo; break;
            case 10: src=gW1; break; case 11: src=gW2; break; default: src=gct; break;
        }
        float v = src[soff[r] + (i<<lout[r]) + j];
        if (sel[r] == 0 || sel[r] == 6) v *= 0.17677669529663689f;
        WT[doff[r] + d] = f2bf_rn(v);
    } else if (b < 3669){   // edge vectors + cutoff + reverse-edge
        int e = (b-3200)*256 + tid;
        if (e >= N_EDGES) return;
        int c = centers[e], nb = neighbors[e];
        int st = c / PER;
        const float* cell = cells + st*9;
        float s0 = shifts[e*3+0], s1 = shifts[e*3+1], s2 = shifts[e*3+2];
        float ex = pos[nb*3+0]-pos[c*3+0] + s0*cell[0]+s1*cell[3]+s2*cell[6];
        float ey = pos[nb*3+1]-pos[c*3+1] + s0*cell[1]+s1*cell[4]+s2*cell[7];
        float ez = pos[nb*3+2]-pos[c*3+2] + s0*cell[2]+s1*cell[5]+s2*cell[8];
        EV[e*3+0] = ex; EV[e*3+1] = ey; EV[e*3+2] = ez;
        RAD[e] = cutoff_f(sqrtf(ex*ex+ey*ey+ez*ez));
        int base2 = nb*K_NB, corr = base2;
        for (int k2 = 0; k2 < K_NB; k2++){
            if (neighbors[base2+k2] == c){ corr = base2+k2; break; }
        }
        CORR[e] = corr;
    } else if (b < 3689){   // element map
        int i = (b-3669)*256 + tid;
        if (i < N_NODES){
            int z = numbers[i];
            ELEM[i] = (z==1)?0:(z==6)?1:(z==7)?2:(z==8)?3:-1;
        }
    } else if (b == 3689){  // encoder weight precontract
        if (tid >= 128) return;
        int j = tid;
        for (int a = 0; a < 3; a++){
            float s = 0;
            for (int i = 0; i < 128; i++) s += Wcart[a*128+i]*Wcomp[i*128+j];
            W3[a*128+j] = s;
        }
        for (int sp = 0; sp < 4; sp++){
            float s1 = 0, s2 = 0;
            for (int i = 0; i < 128; i++){
                s1 += embc[sp*128+i]*Wcomp[(128+i)*128+j];
                s2 += embn[sp*128+i]*Wcomp[(256+i)*128+j];
            }
            ECn[sp*128+j] = s1; ENn[sp*128+j] = s2;
        }
    } else {                // init out with composition term (readout fused elsewhere)
        if (tid < N_STRUCT){
            float s = 0.f;
            for (int nl = 0; nl < PER; nl++){
                int z = numbers[tid*PER + nl];
                int el = (z==1)?0:(z==6)?1:(z==7)?2:3;
                s += cw[el];
            }
            out[tid] = s;
        }
    }
}

// one node per block, 256 threads (8 threads/row)
__global__ __launch_bounds__(256) void k_encode(const float* __restrict__ EV,
                         const float* __restrict__ RAD,
                         const int* __restrict__ centers, const int* __restrict__ neighbors,
                         const int* __restrict__ ELEM, const float* __restrict__ W3,
                         const float* __restrict__ ECn, const float* __restrict__ ENn,
                         float* __restrict__ X, float* __restrict__ RADN){
    int n = blockIdx.x, tid = threadIdx.x;
    int s = tid >> 3, l8 = tid & 7;
    int e = (s < K_NB) ? (n*K_NB + s) : 0;   // padding slots replicate edge 0 (nef_idx=0)
    int ec = ELEM[centers[e]], en = ELEM[neighbors[e]];
    float ev0 = EV[e*3+0], ev1 = EV[e*3+1], ev2 = EV[e*3+2];
    size_t ro = (size_t)(n*32 + s)*128;
    #pragma unroll
    for (int c = 0; c < 4; c++){
        int j = l8*16 + c*4;
        f32x4 wa = *(const f32x4*)&W3[j];
        f32x4 wb = *(const f32x4*)&W3[128+j];
        f32x4 wc = *(const f32x4*)&W3[256+j];
        f32x4 ea = *(const f32x4*)&ECn[ec*128+j];
        f32x4 na = *(const f32x4*)&ENn[en*128+j];
        f32x4 o;
        #pragma unroll
        for (int k = 0; k < 4; k++) o[k] = ev0*wa[k] + ev1*wb[k] + ev2*wc[k] + ea[k] + na[k];
        *(f32x4*)&X[ro + j] = o;
    }
    if (tid < 32) RADN[(size_t)n*32 + tid] = (tid < K_NB) ? RAD[n*K_NB + tid] : 0.f;
}

// ======= Persistent MFMA attention: weights in VGPRs, 35.6 KB LDS, 4 blocks/CU =======
__global__ __launch_bounds__(256, 2) void k_attn_p(float* __restrict__ X,
        const short* __restrict__ Wqt, const short* __restrict__ Wkt,
        const short* __restrict__ Wvt, const short* __restrict__ Wot,
        const float* __restrict__ lnw, const float* __restrict__ lnb,
        const float* __restrict__ radn){
    __shared__ short hh[32*136];    // LN out [t][j]
    __shared__ short Qs[32*136];    // Q[t][j]; aliased OB[t][j] after scores
    __shared__ short Ks[32*136];    // K[s][j]; head h's cols become P[t][s] after scores
    __shared__ short VT[128*40];    // V^T[j][s], mask folded
    __shared__ float radl[32];
    const int tid = threadIdx.x, lane = tid & 63, w = tid >> 6;
    const int quad = lane >> 4, l16 = lane & 15;

    bf16x8 wQ[8], wK[8], wV[8], wO[8];
    #pragma unroll
    for (int mt = 0; mt < 2; mt++)
        #pragma unroll
        for (int kk = 0; kk < 4; kk++){
            int ro = (w*32 + mt*16 + l16)*128 + kk*32 + quad*8;
            wQ[mt*4+kk] = *(const bf16x8*)&Wqt[ro];
            wK[mt*4+kk] = *(const bf16x8*)&Wkt[ro];
            wV[mt*4+kk] = *(const bf16x8*)&Wvt[ro];
            wO[mt*4+kk] = *(const bf16x8*)&Wot[ro];
        }

    for (int node = blockIdx.x; node < N_NODES; node += 1024){
        float* Xn = X + (size_t)node*4096;
        {   // LayerNorm from global -> hh; 8 threads/row
            int row = tid >> 3, l8 = tid & 7;
            f32x4 v[4];
            #pragma unroll
            for (int c = 0; c < 4; c++) v[c] = *(const f32x4*)&Xn[row*128 + l8*16 + c*4];
            float s = 0, ss = 0;
            #pragma unroll
            for (int c = 0; c < 4; c++){
                #pragma unroll
                for (int k = 0; k < 4; k++){ s += v[c][k]; ss += v[c][k]*v[c][k]; }
            }
            #pragma unroll
            for (int m = 1; m < 8; m <<= 1){ s += __shfl_xor(s, m); ss += __shfl_xor(ss, m); }
            float mean = s*(1.f/128.f);
            float rstd = rsqrtf(ss*(1.f/128.f) - mean*mean + 1e-5f);
            #pragma unroll
            for (int c = 0; c < 4; c++){
                f32x4 wv4 = *(const f32x4*)&lnw[l8*16 + c*4];
                f32x4 bv4 = *(const f32x4*)&lnb[l8*16 + c*4];
                short4 pk;
                pk.x = f2bf((v[c][0]-mean)*rstd*wv4[0] + bv4[0]);
                pk.y = f2bf((v[c][1]-mean)*rstd*wv4[1] + bv4[1]);
                pk.z = f2bf((v[c][2]-mean)*rstd*wv4[2] + bv4[2]);
                pk.w = f2bf((v[c][3]-mean)*rstd*wv4[3] + bv4[3]);
                *(short4*)&hh[row*136 + l8*16 + c*4] = pk;
            }
        }
        if (tid < 32) radl[tid] = radn[(size_t)node*32 + tid];
        __syncthreads();                     // (1)

        {   // Q+K pass
            f32x4 z = {0.f,0.f,0.f,0.f};
            f32x4 qacc[4] = {z,z,z,z}, kacc[4] = {z,z,z,z};
            #pragma unroll
            for (int kk = 0; kk < 4; kk++){
                bf16x8 h0 = *(const bf16x8*)&hh[(l16)*136    + kk*32 + quad*8];
                bf16x8 h1 = *(const bf16x8*)&hh[(16+l16)*136 + kk*32 + quad*8];
                #pragma unroll
                for (int mt = 0; mt < 2; mt++){
                    qacc[mt*2+0] = MFMA_B16(wQ[mt*4+kk], h0, qacc[mt*2+0]);
                    qacc[mt*2+1] = MFMA_B16(wQ[mt*4+kk], h1, qacc[mt*2+1]);
                    kacc[mt*2+0] = MFMA_B16(wK[mt*4+kk], h0, kacc[mt*2+0]);
                    kacc[mt*2+1] = MFMA_B16(wK[mt*4+kk], h1, kacc[mt*2+1]);
                }
            }
            #pragma unroll
            for (int mt = 0; mt < 2; mt++){
                #pragma unroll
                for (int nt = 0; nt < 2; nt++){
                    int t = nt*16 + l16, jb = w*32 + mt*16 + quad*4;
                    short4 pk;
                    pk.x = f2bf(qacc[mt*2+nt][0]); pk.y = f2bf(qacc[mt*2+nt][1]);
                    pk.z = f2bf(qacc[mt*2+nt][2]); pk.w = f2bf(qacc[mt*2+nt][3]);
                    *(short4*)&Qs[t*136 + jb] = pk;
                    short4 pk2;
                    pk2.x = f2bf(kacc[mt*2+nt][0]); pk2.y = f2bf(kacc[mt*2+nt][1]);
                    pk2.z = f2bf(kacc[mt*2+nt][2]); pk2.w = f2bf(kacc[mt*2+nt][3]);
                    *(short4*)&Ks[t*136 + jb] = pk2;
                }
            }
        }
        {   // V pass; rad folded
            f32x4 z = {0.f,0.f,0.f,0.f};
            f32x4 vacc[4] = {z,z,z,z};
            #pragma unroll
            for (int kk = 0; kk < 4; kk++){
                bf16x8 h0 = *(const bf16x8*)&hh[(l16)*136    + kk*32 + quad*8];
                bf16x8 h1 = *(const bf16x8*)&hh[(16+l16)*136 + kk*32 + quad*8];
                #pragma unroll
                for (int mt = 0; mt < 2; mt++){
                    vacc[0*2+mt] = MFMA_B16(h0, wV[mt*4+kk], vacc[0*2+mt]);
                    vacc[1*2+mt] = MFMA_B16(h1, wV[mt*4+kk], vacc[1*2+mt]);
                }
            }
            #pragma unroll
            for (int mt = 0; mt < 2; mt++){
                #pragma unroll
                for (int nt = 0; nt < 2; nt++){
                    int j = w*32 + nt*16 + l16, sb = mt*16 + quad*4;
                    f32x4 r4 = *(const f32x4*)&radl[sb];
                    short4 pk;
                    pk.x = f2bf(vacc[mt*2+nt][0]*r4[0]); pk.y = f2bf(vacc[mt*2+nt][1]*r4[1]);
                    pk.z = f2bf(vacc[mt*2+nt][2]*r4[2]); pk.w = f2bf(vacc[mt*2+nt][3]*r4[3]);
                    *(short4*)&VT[j*40 + sb] = pk;
                }
            }
        }
        // no barrier: wave h reads only its own columns below (R5-verified ownership)
        {   // scores + softmax + P (into Ks own col block; in-wave-order safe)
            const int h = w;
            bf16x8 qa0 = *(const bf16x8*)&Qs[(l16)*136    + h*32 + quad*8];
            bf16x8 qa1 = *(const bf16x8*)&Qs[(16+l16)*136 + h*32 + quad*8];
            bf16x8 kb0 = *(const bf16x8*)&Ks[(l16)*136    + h*32 + quad*8];
            bf16x8 kb1 = *(const bf16x8*)&Ks[(16+l16)*136 + h*32 + quad*8];
            f32x4 z = {0.f,0.f,0.f,0.f};
            f32x4 sc00 = MFMA_B16(qa0, kb0, z), sc01 = MFMA_B16(qa0, kb1, z);
            f32x4 sc10 = MFMA_B16(qa1, kb0, z), sc11 = MFMA_B16(qa1, kb1, z);
            #pragma unroll
            for (int mt = 0; mt < 2; mt++){
                f32x4 s0 = mt ? sc10 : sc00, s1 = mt ? sc11 : sc01;
                #pragma unroll
                for (int r = 0; r < 4; r++){
                    float mx = fmaxf(s0[r], s1[r]);
                    #pragma unroll
                    for (int dlt = 1; dlt < 16; dlt <<= 1) mx = fmaxf(mx, __shfl_xor(mx, dlt));
                    float e0 = __expf(s0[r]-mx), e1 = __expf(s1[r]-mx);
                    float sm = e0 + e1;
                    #pragma unroll
                    for (int dlt = 1; dlt < 16; dlt <<= 1) sm += __shfl_xor(sm, dlt);
                    float inv = __builtin_amdgcn_rcpf(sm);
                    int t = mt*16 + quad*4 + r;
                    Ks[t*136 + h*32 + l16]      = f2bf(e0*inv);
                    Ks[t*136 + h*32 + 16 + l16] = f2bf(e1*inv);
                }
            }
        }
        short* OB = Qs;
        {   // PV
            const int h = w;
            bf16x8 pa0 = *(const bf16x8*)&Ks[(l16)*136    + h*32 + quad*8];
            bf16x8 pa1 = *(const bf16x8*)&Ks[(16+l16)*136 + h*32 + quad*8];
            bf16x8 vb0 = *(const bf16x8*)&VT[(h*32 + l16)*40      + quad*8];
            bf16x8 vb1 = *(const bf16x8*)&VT[(h*32 + 16 + l16)*40 + quad*8];
            f32x4 z = {0.f,0.f,0.f,0.f};
            f32x4 o00 = MFMA_B16(pa0, vb0, z), o01 = MFMA_B16(pa0, vb1, z);
            f32x4 o10 = MFMA_B16(pa1, vb0, z), o11 = MFMA_B16(pa1, vb1, z);
            #pragma unroll
            for (int mt = 0; mt < 2; mt++){
                #pragma unroll
                for (int nt = 0; nt < 2; nt++){
                    f32x4 ov = mt ? (nt ? o11 : o10) : (nt ? o01 : o00);
                    int j = w*32 + nt*16 + l16;
                    #pragma unroll
                    for (int r = 0; r < 4; r++){
                        int t = mt*16 + quad*4 + r;
                        OB[t*136 + j] = f2bf(ov[r]);
                    }
                }
            }
        }
        __syncthreads();                     // (2)
        {   // O-projection + residual RMW -> global (lines L2-hot from LN read)
            f32x4 z = {0.f,0.f,0.f,0.f};
            f32x4 oc[4] = {z,z,z,z};
            #pragma unroll
            for (int kk = 0; kk < 4; kk++){
                bf16x8 a0 = *(const bf16x8*)&OB[(l16)*136    + kk*32 + quad*8];
                bf16x8 a1 = *(const bf16x8*)&OB[(16+l16)*136 + kk*32 + quad*8];
                #pragma unroll
                for (int nt = 0; nt < 2; nt++){
                    oc[0+nt] = MFMA_B16(a0, wO[nt*4+kk], oc[0+nt]);
                    oc[2+nt] = MFMA_B16(a1, wO[nt*4+kk], oc[2+nt]);
                }
            }
            #pragma unroll
            for (int mt = 0; mt < 2; mt++){
                #pragma unroll
                for (int nt = 0; nt < 2; nt++){
                    int j2 = w*32 + nt*16 + l16;
                    #pragma unroll
                    for (int r = 0; r < 4; r++){
                        int t = mt*16 + quad*4 + r;
                        Xn[t*128 + j2] += oc[mt*2+nt][r];
                    }
                }
            }
        }
        // loop-end barrier removed (safe: hh/radl readers finish before barrier(2);
        // Qs/Ks/VT writes happen only after next barrier(1))
    }
}

// ======= Persistent MFMA FFN (xs residual, 3 barriers); optional fused Y-readout =======
__global__ __launch_bounds__(512, 2) void k_ffn_p(float* __restrict__ X,
        const short* __restrict__ W1t, const short* __restrict__ W2t,
        const float* __restrict__ B1, const float* __restrict__ B2,
        const float* __restrict__ lnw, const float* __restrict__ lnb,
        const float* __restrict__ rW, const float* __restrict__ radn,
        float* __restrict__ out){
    __shared__ float xs[32*132];     // fp32 residual
    __shared__ short hh[32*136];     // LN out bf16
    __shared__ short mid[32*520];    // gelu out bf16
    __shared__ float radl2[32];
    __shared__ float wsumR[8];
    const int tid = threadIdx.x, lane = tid & 63, w = tid >> 6;
    const int quad = lane >> 4, l16 = lane & 15;

    bf16x8 wA[16];
    #pragma unroll
    for (int mt = 0; mt < 4; mt++)
        #pragma unroll
        for (int kk = 0; kk < 4; kk++)
            wA[mt*4+kk] = *(const bf16x8*)&W1t[(size_t)(w*64+mt*16+l16)*128 + kk*32 + quad*8];
    bf16x8 wB[16];
    #pragma unroll
    for (int kk = 0; kk < 16; kk++)
        wB[kk] = *(const bf16x8*)&W2t[(size_t)(w*16+l16)*512 + kk*32 + quad*8];
    f32x4 bb1[4];
    #pragma unroll
    for (int mt = 0; mt < 4; mt++) bb1[mt] = *(const f32x4*)&B1[w*64 + mt*16 + quad*4];
    const float b2v = B2[w*16 + l16];
    const float rwv = rW ? rW[w*16 + l16] : 0.f;

    for (int tile = blockIdx.x; tile < NTOK/32; tile += 512){
        float* Xg = X + (size_t)tile*4096;
        {   // load + LN: 16 threads/row, 8 floats each
            int row = tid >> 4, lc = tid & 15;
            f32x4 v0 = *(const f32x4*)&Xg[row*128 + lc*8];
            f32x4 v1 = *(const f32x4*)&Xg[row*128 + lc*8 + 4];
            *(f32x4*)&xs[row*132 + lc*8]     = v0;
            *(f32x4*)&xs[row*132 + lc*8 + 4] = v1;
            float s = 0, ss = 0;
            #pragma unroll
            for (int k = 0; k < 4; k++){ s += v0[k]+v1[k]; ss += v0[k]*v0[k]+v1[k]*v1[k]; }
            #pragma unroll
            for (int m = 1; m < 16; m <<= 1){ s += __shfl_xor(s, m); ss += __shfl_xor(ss, m); }
            float mean = s*(1.f/128.f);
            float rstd = rsqrtf(ss*(1.f/128.f) - mean*mean + 1e-5f);
            f32x4 w0 = *(const f32x4*)&lnw[lc*8], w1 = *(const f32x4*)&lnw[lc*8+4];
            f32x4 g0 = *(const f32x4*)&lnb[lc*8], g1 = *(const f32x4*)&lnb[lc*8+4];
            short4 pa, pb;
            pa.x = f2bf((v0[0]-mean)*rstd*w0[0] + g0[0]);
            pa.y = f2bf((v0[1]-mean)*rstd*w0[1] + g0[1]);
            pa.z = f2bf((v0[2]-mean)*rstd*w0[2] + g0[2]);
            pa.w = f2bf((v0[3]-mean)*rstd*w0[3] + g0[3]);
            pb.x = f2bf((v1[0]-mean)*rstd*w1[0] + g1[0]);
            pb.y = f2bf((v1[1]-mean)*rstd*w1[1] + g1[1]);
            pb.z = f2bf((v1[2]-mean)*rstd*w1[2] + g1[2]);
            pb.w = f2bf((v1[3]-mean)*rstd*w1[3] + g1[3]);
            *(short4*)&hh[row*136 + lc*8]     = pa;
            *(short4*)&hh[row*136 + lc*8 + 4] = pb;
        }
        if (rW && tid < 32) radl2[tid] = radn[(size_t)tile*32 + tid];
        __syncthreads();
        {   // FFN1: D[m=ff][n=t]; wave m-range [w*64,+64)
            f32x4 z = {0.f,0.f,0.f,0.f};
            f32x4 acc[8];
            #pragma unroll
            for (int i = 0; i < 8; i++) acc[i] = z;
            #pragma unroll
            for (int kk = 0; kk < 4; kk++){
                bf16x8 h0 = *(const bf16x8*)&hh[(l16)*136    + kk*32 + quad*8];
                bf16x8 h1 = *(const bf16x8*)&hh[(16+l16)*136 + kk*32 + quad*8];
                #pragma unroll
                for (int mt = 0; mt < 4; mt++){
                    acc[mt*2+0] = MFMA_B16(wA[mt*4+kk], h0, acc[mt*2+0]);
                    acc[mt*2+1] = MFMA_B16(wA[mt*4+kk], h1, acc[mt*2+1]);
                }
            }
            #pragma unroll
            for (int mt = 0; mt < 4; mt++){
                int fb = w*64 + mt*16 + quad*4;
                #pragma unroll
                for (int nt = 0; nt < 2; nt++){
                    int t = nt*16 + l16;
                    short4 pk;
                    pk.x = f2bf(gelu_f(acc[mt*2+nt][0] + bb1[mt][0]));
                    pk.y = f2bf(gelu_f(acc[mt*2+nt][1] + bb1[mt][1]));
                    pk.z = f2bf(gelu_f(acc[mt*2+nt][2] + bb1[mt][2]));
                    pk.w = f2bf(gelu_f(acc[mt*2+nt][3] + bb1[mt][3]));
                    *(short4*)&mid[t*520 + fb] = pk;
                }
            }
        }
        __syncthreads();
        {   // FFN2 + residual / fused Y-readout
            f32x4 z = {0.f,0.f,0.f,0.f};
            f32x4 o0 = z, o1 = z;
            #pragma unroll
            for (int kk = 0; kk < 16; kk++){
                bf16x8 a0 = *(const bf16x8*)&mid[(l16)*520    + kk*32 + quad*8];
                bf16x8 a1 = *(const bf16x8*)&mid[(16+l16)*520 + kk*32 + quad*8];
                o0 = MFMA_B16(a0, wB[kk], o0);
                o1 = MFMA_B16(a1, wB[kk], o1);
            }
            int j = w*16 + l16;
            if (!rW){
                #pragma unroll
                for (int r = 0; r < 4; r++){
                    int t0 = quad*4 + r, t1 = 16 + quad*4 + r;
                    Xg[t0*128 + j] = xs[t0*132 + j] + o0[r] + b2v;
                    Xg[t1*128 + j] = xs[t1*132 + j] + o1[r] + b2v;
                }
            } else {
                float part = 0.f;
                #pragma unroll
                for (int r = 0; r < 4; r++){
                    int t0 = quad*4 + r, t1 = 16 + quad*4 + r;
                    float y0 = xs[t0*132 + j] + o0[r] + b2v;
                    float y1 = xs[t1*132 + j] + o1[r] + b2v;
                    part += y0 * radl2[t0] + y1 * radl2[t1];
                }
                part *= rwv;
                #pragma unroll
                for (int m = 1; m < 64; m <<= 1) part += __shfl_xor(part, m);
                if (lane == 0) wsumR[w] = part;
            }
        }
        __syncthreads();
        if (rW && tid == 0){
            float tot = 0.f;
            #pragma unroll
            for (int i = 0; i < 8; i++) tot += wsumR[i];
            atomicAdd(&out[tile/PER], tot);
        }
    }
}

// ---- MFMA edge contraction: 32 edges/block; also accumulates the X readout term ----
__global__ __launch_bounds__(256) void k_contract_mfma(const float* __restrict__ X,
        const int* __restrict__ centers, const int* __restrict__ CORR,
        const short* __restrict__ gct, float* __restrict__ Y,
        const float* __restrict__ rW, const float* __restrict__ RADN,
        float* __restrict__ out){
    __shared__ short ab[32*264];    // [edge][256 concat feats]
    __shared__ float red[4];
    const int tid = threadIdx.x, lane = tid & 63, w = tid >> 6;
    const int quad = lane >> 4, l16 = lane & 15;
    const int e0 = blockIdx.x*32;
    float px = 0.f;
    for (int idx = tid; idx < 2048; idx += 256){
        int r = idx >> 6, c4 = idx & 63;
        int e = e0 + r, srcRow;
        bool own = (c4 < 32);
        if (own){ int c = centers[e]; srcRow = c*32 + (e - c*K_NB); }
        else    { int ec = CORR[e]; int c = centers[ec]; srcRow = c*32 + (ec - c*K_NB); }
        float4 v = *(const float4*)&X[(size_t)srcRow*128 + (c4 & 31)*4];
        if (own){
            float4 rw4 = *(const float4*)&rW[(c4 & 31)*4];
            px += (v.x*rw4.x + v.y*rw4.y + v.z*rw4.z + v.w*rw4.w) * RADN[srcRow];
        }
        short4 pk; pk.x = f2bf(v.x); pk.y = f2bf(v.y); pk.z = f2bf(v.z); pk.w = f2bf(v.w);
        *(short4*)&ab[r*264 + c4*4] = pk;
    }
    #pragma unroll
    for (int m = 1; m < 64; m <<= 1) px += __shfl_xor(px, m);
    if (lane == 0) red[w] = px;
    __syncthreads();
    if (tid == 0) atomicAdd(&out[blockIdx.x/75], red[0]+red[1]+red[2]+red[3]);
    f32x4 z = {0.f,0.f,0.f,0.f};
    f32x4 o[4] = {z,z,z,z};
    #pragma unroll
    for (int kk = 0; kk < 8; kk++){
        bf16x8 a0 = *(const bf16x8*)&ab[(l16)*264    + kk*32 + quad*8];
        bf16x8 a1 = *(const bf16x8*)&ab[(16+l16)*264 + kk*32 + quad*8];
        #pragma unroll
        for (int nt = 0; nt < 2; nt++){
            bf16x8 bw = *(const bf16x8*)&gct[(size_t)(w*32+nt*16+l16)*256 + kk*32 + quad*8];
            o[0+nt] = MFMA_B16(a0, bw, o[0+nt]);
            o[2+nt] = MFMA_B16(a1, bw, o[2+nt]);
        }
    }
    #pragma unroll
    for (int mt = 0; mt < 2; mt++){
        #pragma unroll
        for (int nt = 0; nt < 2; nt++){
            int j = w*32 + nt*16 + l16;
            #pragma unroll
            for (int r = 0; r < 4; r++){
                int e = e0 + mt*16 + quad*4 + r;
                int c = e / K_NB, slot = e - c*K_NB;
                Y[((size_t)c*32 + slot)*128 + j] = o[mt*2+nt][r];
            }
        }
    }
}

__global__ void k_padfill(float* __restrict__ Y){
    int idx = blockIdx.x*256 + threadIdx.x;
    if (idx >= N_NODES*8*D) return;
    int j = idx & 127, rs = idx >> 7;
    int n = rs >> 3, sr = rs & 7;
    Y[((size_t)n*32 + K_NB + sr)*D + j] = Y[j];   // contracted edge 0 (nef_idx=0)
}

extern "C" void kernel_launch(void* const* d_in, const int* in_sizes, int n_in,
                              void* d_out, int out_size, void* d_ws, size_t ws_size,
                              hipStream_t stream){
    const float* positions   = (const float*)d_in[0];
    const float* cells       = (const float*)d_in[1];
    const float* cell_shifts = (const float*)d_in[2];
    const float* enc_Wcart   = (const float*)d_in[3];
    const float* enc_emb_c   = (const float*)d_in[4];
    const float* enc_emb_n   = (const float*)d_in[5];
    const float* enc_Wcomp   = (const float*)d_in[6];
    const float* t_Wq  = (const float*)d_in[7];
    const float* t_Wk  = (const float*)d_in[8];
    const float* t_Wv  = (const float*)d_in[9];
    const float* t_Wo  = (const float*)d_in[10];
    const float* t_ln1w = (const float*)d_in[11];
    const float* t_ln1b = (const float*)d_in[12];
    const float* t_ln2w = (const float*)d_in[13];
    const float* t_ln2b = (const float*)d_in[14];
    const float* t_W1  = (const float*)d_in[15];
    const float* t_b1  = (const float*)d_in[16];
    const float* t_W2  = (const float*)d_in[17];
    const float* t_b2  = (const float*)d_in[18];
    const float* g_contr = (const float*)d_in[19];
    const float* g_Wq  = (const float*)d_in[20];
    const float* g_Wk  = (const float*)d_in[21];
    const float* g_Wv  = (const float*)d_in[22];
    const float* g_Wo  = (const float*)d_in[23];
    const float* g_ln1w = (const float*)d_in[24];
    const float* g_ln1b = (const float*)d_in[25];
    const float* g_ln2w = (const float*)d_in[26];
    const float* g_ln2b = (const float*)d_in[27];
    const float* g_W1  = (const float*)d_in[28];
    const float* g_b1  = (const float*)d_in[29];
    const float* g_W2  = (const float*)d_in[30];
    const float* g_b2  = (const float*)d_in[31];
    const float* readout_W = (const float*)d_in[32];
    const float* comp_w    = (const float*)d_in[33];
    const int* numbers   = (const int*)d_in[34];
    const int* centers   = (const int*)d_in[35];
    const int* neighbors = (const int*)d_in[36];

    float* ws = (float*)d_ws;
    float* X    = ws;                       // NTOK*D
    float* Y    = X + (size_t)NTOK*D;       // NTOK*D
    float* EV   = Y + (size_t)NTOK*D;       // N_EDGES*3
    float* RAD  = EV + (size_t)N_EDGES*3;   // N_EDGES
    float* RADN = RAD + N_EDGES;            // NTOK
    float* W3   = RADN + NTOK;              // 3*128
    float* ECn  = W3 + 3*128;               // 4*128
    float* ENn  = ECn + 4*128;              // 4*128
    int*   ELEM = (int*)(ENn + 4*128);      // N_NODES
    int*   CORR = ELEM + N_NODES;           // N_EDGES
    short* WT   = (short*)(CORR + N_EDGES); // 819200 bf16 elems

    const short *tWqt = WT,           *tWkt = WT + 32768, *tWvt = WT + 65536, *tWot = WT + 98304;
    const short *tW1t = WT + 131072,  *tW2t = WT + 262144;
    const short *gWqt = WT + 393216,  *gWkt = WT + 425984, *gWvt = WT + 458752, *gWot = WT + 491520;
    const short *gW1t = WT + 524288,  *gW2t = WT + 655360, *gctT = WT + 786432;

    k_setup<<<3691, 256, 0, stream>>>(t_Wq, t_Wk, t_Wv, t_Wo, t_W1, t_W2,
                                      g_Wq, g_Wk, g_Wv, g_Wo, g_W1, g_W2, g_contr, WT,
                                      positions, cells, cell_shifts, centers, neighbors,
                                      EV, RAD, CORR, numbers, ELEM,
                                      enc_Wcart, enc_emb_c, enc_emb_n, enc_Wcomp,
                                      W3, ECn, ENn, comp_w, (float*)d_out);
    k_encode<<<N_NODES, 256, 0, stream>>>(EV, RAD, centers, neighbors, ELEM, W3, ECn, ENn, X, RADN);

    for (int l = 0; l < 2; l++){
        k_attn_p<<<1024, 256, 0, stream>>>(X, tWqt + l*16384, tWkt + l*16384,
                                           tWvt + l*16384, tWot + l*16384,
                                           t_ln1w + l*128, t_ln1b + l*128, RADN);
        k_ffn_p<<<512, 512, 0, stream>>>(X, tW1t + l*65536, tW2t + l*65536,
                                         t_b1 + l*512, t_b2 + l*128,
                                         t_ln2w + l*128, t_ln2b + l*128,
                                         nullptr, nullptr, nullptr);
    }

    // contract also accumulates the X part of the readout (X is final here)
    k_contract_mfma<<<N_EDGES/32, 256, 0, stream>>>(X, centers, CORR, gctT, Y,
                                                    readout_W, RADN, (float*)d_out);
    k_padfill<<<(N_NODES*8*D+255)/256, 256, 0, stream>>>(Y);

    for (int l = 0; l < 2; l++){
        k_attn_p<<<1024, 256, 0, stream>>>(Y, gWqt + l*16384, gWkt + l*16384,
                                           gWvt + l*16384, gWot + l*16384,
                                           g_ln1w + l*128, g_ln1b + l*128, RADN);
        k_ffn_p<<<512, 512, 0, stream>>>(Y, gW1t + l*65536, gW2t + l*65536,
                                         g_b1 + l*512, g_b2 + l*128,
                                         g_ln2w + l*128, g_ln2b + l*128,
                                         (l == 1) ? readout_W : nullptr,
                                         (l == 1) ? RADN : nullptr,
                                         (l == 1) ? (float*)d_out : nullptr);
    }
}